// Round 8
// baseline (264.710 us; speedup 1.0000x reference)
//
#include <hip/hip_runtime.h>
#include <hip/hip_bf16.h>
#include <stdint.h>
#include <math.h>

#define BB 4
#define NN 2048
#define NFEAT 256
#define NHID 64
#define NHEADS 4
#define NCLASS 32
#define KK1 256
#define ALPHA 0.2f
#define LOG2E 1.4426950408889634f

typedef _Float16 f16x8 __attribute__((ext_vector_type(8)));
typedef _Float16 h16x2 __attribute__((ext_vector_type(2)));
typedef float f32x4 __attribute__((ext_vector_type(4)));

__device__ __forceinline__ f16x8 ldb128(const _Float16* p){
  f16x8 r;
  *(uint4*)&r = *(const uint4*)p;     // single ds_read_b128 (16B-aligned)
  return r;
}

__device__ __forceinline__ h16x2 pk2(float a, float b){
  auto v = __builtin_amdgcn_cvt_pkrtz(a, b);
  h16x2 r;
  __builtin_memcpy(&r, &v, sizeof(r));
  return r;
}

// ---------------- K0: pack adj int32 -> bitmask + per-row count ---------
__global__ void __launch_bounds__(256) pack_adj(const int* __restrict__ adj,
                                                unsigned long long* __restrict__ bits,
                                                int* __restrict__ cnt){
  __shared__ int csum[4];
  int row = blockIdx.x;                       // b*N + i
  const int* arow = adj + (size_t)row * NN;
  int lane = threadIdx.x & 63, wv = threadIdx.x >> 6;
  int c = 0;
  #pragma unroll
  for (int it=0; it<NN/256; ++it){
    int j = it*256 + threadIdx.x;
    unsigned long long m = __ballot(arow[j] > 0);
    if (lane==0){ bits[(size_t)row*(NN/64) + it*4 + wv] = m; c += __popcll(m); }
  }
  if (lane==0) csum[wv] = c;
  __syncthreads();
  if (threadIdx.x==0) cnt[row] = csum[0]+csum[1]+csum[2]+csum[3];
}

// ---- K1: WhT(f16) = (x@W)^T per head; store exp2-domain attn factors ---
// ex1=exp2(f1*log2e), gx1=exp2(0.2*f1*log2e); ex2/gx2 same for f2.
__global__ void __launch_bounds__(256) wh_proj2(const float* __restrict__ x,
        const float* __restrict__ W, const float* __restrict__ a1, const float* __restrict__ a2,
        _Float16* __restrict__ whT,
        float* __restrict__ ex1, float* __restrict__ gx1,
        float* __restrict__ ex2, float* __restrict__ gx2){
  __shared__ __align__(16) float xs[64*65];
  __shared__ float red1[4][64];
  __shared__ float red2[4][64];
  int bh = blockIdx.x >> 5;
  int i0 = (blockIdx.x & 31) * 64;
  int b = bh >> 2, h = bh & 3;
  int tid = threadIdx.x;
  int lane = tid & 63;
  int dbase = __builtin_amdgcn_readfirstlane(tid >> 6) * 16;
  float acc[16];
  #pragma unroll
  for (int dd=0; dd<16; ++dd) acc[dd] = 0.f;
  for (int kc=0; kc<4; ++kc){
    int kb = kc*64;
    __syncthreads();
    #pragma unroll
    for (int t=0; t<4; ++t){
      int row = t*16 + (tid>>4);
      int f4 = (tid&15)*4;
      float4 v = *(const float4*)(x + ((size_t)(b*NN + i0 + row))*NFEAT + kb + f4);
      xs[row*65 + f4 + 0] = v.x;
      xs[row*65 + f4 + 1] = v.y;
      xs[row*65 + f4 + 2] = v.z;
      xs[row*65 + f4 + 3] = v.w;
    }
    __syncthreads();
    const float* Wb = W + (size_t)h*NFEAT*NHID + (size_t)kb*NHID + dbase;
    #pragma unroll 4
    for (int f=0; f<64; ++f){
      float xv = xs[lane*65 + f];
      const float* wr = Wb + f*NHID;
      #pragma unroll
      for (int dd=0; dd<16; ++dd) acc[dd] = fmaf(xv, wr[dd], acc[dd]);
    }
  }
  float p1 = 0.f, p2 = 0.f;
  #pragma unroll
  for (int dd=0; dd<16; ++dd){
    int d = dbase + dd;
    whT[((size_t)bh*NHID + d)*NN + i0 + lane] = (_Float16)acc[dd];
    p1 = fmaf(acc[dd], a1[h*NHID + d], p1);
    p2 = fmaf(acc[dd], a2[h*NHID + d], p2);
  }
  int wv = tid >> 6;
  red1[wv][lane] = p1;
  red2[wv][lane] = p2;
  __syncthreads();
  if (tid < 64){
    float s1 = (red1[0][tid]+red1[1][tid]+red1[2][tid]+red1[3][tid]) * LOG2E;
    float s2 = (red2[0][tid]+red2[1][tid]+red2[2][tid]+red2[3][tid]) * LOG2E;
    size_t o = (size_t)bh*NN + i0 + tid;
    ex1[o] = __builtin_amdgcn_exp2f(s1);
    gx1[o] = __builtin_amdgcn_exp2f(ALPHA*s1);
    ex2[o] = __builtin_amdgcn_exp2f(s2);
    gx2[o] = __builtin_amdgcn_exp2f(ALPHA*s2);
  }
}

// ---- K2: h1 = elu(softmax(e)@Wh); wave-j-split, exp-free weights -------
// grid = bh(16) x tile(128): one 16-row m-tile per block; wave w owns
// j in [w*512, w*512+512). Weight = bit ? max(E1*E2[j], G1*G2[j]) : fz,
// fz = (cnt==0), which reproduces the uniform-softmax empty-row case
// exactly (l sums to N). B tile 64d x 128j in LDS pitch 136 (17x16B:
// b128 ops, 2-way banks = free). Epilogue reuses B LDS as cred.
__global__ void __launch_bounds__(256, 8) attn_l1(
        const unsigned long long* __restrict__ bits,
        const _Float16* __restrict__ whT,
        const float* __restrict__ ex1, const float* __restrict__ gx1,
        const float* __restrict__ ex2, const float* __restrict__ gx2,
        const int* __restrict__ cnt_in,
        float* __restrict__ dst){
  const int PITCH = 136;
  __shared__ __align__(16) _Float16 whs[64*PITCH];   // 17408 B, reused as cred
  __shared__ float lred[4][16];
  int tile = blockIdx.x & 127;
  int bh = blockIdx.x >> 7;
  int b = bh >> 2, h = bh & 3;
  int i0 = tile*16;
  int tid = threadIdx.x;
  int lane = tid & 63, w = tid >> 6;
  int q = lane >> 4, col = lane & 15;
  int mrow = i0 + col;
  size_t ro = (size_t)bh*NN + mrow;
  float E1 = ex1[ro], G1 = gx1[ro];
  float fz = (cnt_in[b*NN + mrow] == 0) ? 1.f : 0.f;
  const unsigned int* mr = (const unsigned int*)(bits + ((size_t)(b*NN + mrow))*(NN/64));
  const float* e2p = ex2 + (size_t)bh*NN;
  const float* g2p = gx2 + (size_t)bh*NN;
  const _Float16* whg = whT + (size_t)bh*NHID*NN;
  // staging: thread -> (d-row sd, j-slice ss); 64B contiguous per thread
  int sd = tid >> 2, ss = tid & 3;
  const _Float16* sg = whg + (size_t)sd*NN + ss*512;
  _Float16* sl = whs + sd*PITCH + ss*32;
  float lacc = 0.f;
  f32x4 acc[4];
  #pragma unroll
  for (int nt=0; nt<4; ++nt) acc[nt] = f32x4{0.f,0.f,0.f,0.f};

  for (int it=0; it<16; ++it){
    __syncthreads();
    {
      const uint4* g4 = (const uint4*)(sg + it*32);
      uint4 t0 = g4[0], t1 = g4[1], t2 = g4[2], t3 = g4[3];
      uint4* l4 = (uint4*)sl;
      l4[0]=t0; l4[1]=t1; l4[2]=t2; l4[3]=t3;
    }
    unsigned int mw = mr[w*16 + it] >> (q*8);
    int jb = w*512 + it*32 + q*8;
    float4 ea = *(const float4*)(e2p + jb);
    float4 eb = *(const float4*)(e2p + jb + 4);
    float4 ga = *(const float4*)(g2p + jb);
    float4 gb = *(const float4*)(g2p + jb + 4);
    __syncthreads();
    float ev[8] = {ea.x,ea.y,ea.z,ea.w, eb.x,eb.y,eb.z,eb.w};
    float gv[8] = {ga.x,ga.y,ga.z,ga.w, gb.x,gb.y,gb.z,gb.w};
    union { f16x8 v; h16x2 hh[4]; } ua;
    #pragma unroll
    for (int p=0; p<4; ++p){
      float w0 = ((mw>>(2*p))&1u)   ? fmaxf(E1*ev[2*p],   G1*gv[2*p])   : fz;
      float w1 = ((mw>>(2*p+1))&1u) ? fmaxf(E1*ev[2*p+1], G1*gv[2*p+1]) : fz;
      lacc += w0 + w1;
      ua.hh[p] = pk2(w0, w1);
    }
    #pragma unroll
    for (int nt=0; nt<4; ++nt){
      f16x8 bv = ldb128(&whs[(nt*16 + col)*PITCH + w*32 + q*8]);
      acc[nt] = __builtin_amdgcn_mfma_f32_16x16x32_f16(ua.v, bv, acc[nt], 0, 0, 0);
    }
  }
  lacc += __shfl_xor(lacc, 16, 64);
  lacc += __shfl_xor(lacc, 32, 64);
  if (q == 0) lred[w][col] = lacc;
  __syncthreads();                      // all B reads done; whs reusable
  float* cred = (float*)whs;            // [4][16][68] = 17408 B
  #pragma unroll
  for (int nt=0; nt<4; ++nt)
    #pragma unroll
    for (int reg=0; reg<4; ++reg)
      cred[(w*16 + q*4 + reg)*68 + nt*16 + col] = acc[nt][reg];
  __syncthreads();
  // combine: thread t -> row t>>4, 4 d's at (t&15)*4
  int row = tid >> 4, dg = (tid & 15) * 4;
  float l = lred[0][row] + lred[1][row] + lred[2][row] + lred[3][row];
  float il = 1.0f / l;
  float4 s = {0,0,0,0};
  #pragma unroll
  for (int ww=0; ww<4; ++ww){
    float4 v = *(const float4*)&cred[(ww*16 + row)*68 + dg];
    s.x+=v.x; s.y+=v.y; s.z+=v.z; s.w+=v.w;
  }
  float ov[4] = {s.x,s.y,s.z,s.w};
  #pragma unroll
  for (int dd=0; dd<4; ++dd){
    float v = ov[dd]*il;
    ov[dd] = v > 0.f ? v : expm1f(v);
  }
  *(float4*)(dst + ((size_t)(b*NN + i0 + row))*(NHEADS*NHID) + h*NHID + dg)
      = float4{ov[0],ov[1],ov[2],ov[3]};
}

// ---- K3a: Wh2T(f16) = (h1@Wo)^T; exp2-domain factors for layer 2 -------
__global__ void __launch_bounds__(256) out_proj2(const float* __restrict__ h1,
        const float* __restrict__ Wo, const float* __restrict__ ao1, const float* __restrict__ ao2,
        _Float16* __restrict__ whT2,
        float* __restrict__ eo1, float* __restrict__ go1,
        float* __restrict__ eo2, float* __restrict__ go2){
  __shared__ __align__(16) float xs[64*65];
  __shared__ float red1[4][64];
  __shared__ float red2[4][64];
  int b = blockIdx.x >> 5;
  int i0 = (blockIdx.x & 31) * 64;
  int tid = threadIdx.x;
  int lane = tid & 63;
  int dbase = __builtin_amdgcn_readfirstlane(tid >> 6) * 8;
  float acc[8];
  #pragma unroll
  for (int dd=0; dd<8; ++dd) acc[dd] = 0.f;
  for (int kc=0; kc<4; ++kc){
    int kb = kc*64;
    __syncthreads();
    #pragma unroll
    for (int t=0; t<4; ++t){
      int row = t*16 + (tid>>4);
      int f4 = (tid&15)*4;
      float4 v = *(const float4*)(h1 + ((size_t)(b*NN + i0 + row))*256 + kb + f4);
      xs[row*65 + f4 + 0] = v.x;
      xs[row*65 + f4 + 1] = v.y;
      xs[row*65 + f4 + 2] = v.z;
      xs[row*65 + f4 + 3] = v.w;
    }
    __syncthreads();
    #pragma unroll 4
    for (int f=0; f<64; ++f){
      float xv = xs[lane*65 + f];
      const float* wr = Wo + (size_t)(kb+f)*NCLASS + dbase;
      #pragma unroll
      for (int dd=0; dd<8; ++dd) acc[dd] = fmaf(xv, wr[dd], acc[dd]);
    }
  }
  float p1 = 0.f, p2 = 0.f;
  #pragma unroll
  for (int dd=0; dd<8; ++dd){
    int d = dbase + dd;
    whT2[((size_t)b*NCLASS + d)*NN + i0 + lane] = (_Float16)acc[dd];
    p1 = fmaf(acc[dd], ao1[d], p1);
    p2 = fmaf(acc[dd], ao2[d], p2);
  }
  int wv = tid >> 6;
  red1[wv][lane] = p1;
  red2[wv][lane] = p2;
  __syncthreads();
  if (tid < 64){
    float s1 = (red1[0][tid]+red1[1][tid]+red1[2][tid]+red1[3][tid]) * LOG2E;
    float s2 = (red2[0][tid]+red2[1][tid]+red2[2][tid]+red2[3][tid]) * LOG2E;
    size_t o = (size_t)b*NN + i0 + tid;
    eo1[o] = __builtin_amdgcn_exp2f(s1);
    go1[o] = __builtin_amdgcn_exp2f(ALPHA*s1);
    eo2[o] = __builtin_amdgcn_exp2f(s2);
    go2[o] = __builtin_amdgcn_exp2f(ALPHA*s2);
  }
}

// ---- K3b: layer-2 attention, gathered rows only, j-split x8 ------------
__global__ void __launch_bounds__(256) attn_l2(
        const unsigned long long* __restrict__ bits,
        const _Float16* __restrict__ whT2,
        const float* __restrict__ eo1, const float* __restrict__ go1,
        const float* __restrict__ eo2, const float* __restrict__ go2,
        const int* __restrict__ cnt_in, const int* __restrict__ oh,
        float* __restrict__ pc, float* __restrict__ pl){
  const int JC = 128, PITCH = 136;
  __shared__ __align__(16) _Float16 whs[32*PITCH];
  __shared__ __align__(16) _Float16 wts[32*PITCH];
  int blk = blockIdx.x;
  int js = blk & 7, kt = (blk>>3) & 7, b = blk >> 6;
  int tid = threadIdx.x;
  int lane = tid & 63, wv = tid >> 6;
  int q = lane >> 4, col = lane & 15;
  int r = tid >> 3, jg = (tid & 7) * 16;
  int row_i = oh[b*KK1 + kt*32 + r];
  float E1 = eo1[b*NN + row_i], G1 = go1[b*NN + row_i];
  float fz = (cnt_in[b*NN + row_i] == 0) ? 1.f : 0.f;
  const unsigned short* mrow = (const unsigned short*)(bits + ((size_t)(b*NN + row_i))*(NN/64));
  const float* e2p = eo2 + (size_t)b*NN;
  const float* g2p = go2 + (size_t)b*NN;
  const _Float16* whg = whT2 + (size_t)b*NCLASS*NN;
  float lacc = 0.f;
  f32x4 c0 = {0.f,0.f,0.f,0.f};
  int mt = wv & 1, nt = wv >> 1;
  for (int ii=0; ii<2; ++ii){
    int it = js*2 + ii;
    __syncthreads();
    #pragma unroll
    for (int dd=0; dd<2; ++dd){
      int d = (tid>>4) + dd*16;
      int j8 = (tid&15)*8;
      *(uint4*)&whs[d*PITCH + j8] = *(const uint4*)(whg + (size_t)d*NN + it*JC + j8);
    }
    {
      unsigned int m16 = mrow[it*8 + (tid&7)];
      const float* ep = e2p + it*JC + jg;
      const float* gp = g2p + it*JC + jg;
      float ev[16], gv[16];
      #pragma unroll
      for (int t4=0; t4<4; ++t4){
        *(float4*)&ev[t4*4] = *(const float4*)(ep + t4*4);
        *(float4*)&gv[t4*4] = *(const float4*)(gp + t4*4);
      }
      union { h16x2 hh[8]; uint4 u4[2]; } wp;
      #pragma unroll
      for (int p=0; p<8; ++p){
        float w0 = (m16 & (1u<<(2*p)))   ? fmaxf(E1*ev[2*p],   G1*gv[2*p])   : fz;
        float w1 = (m16 & (1u<<(2*p+1))) ? fmaxf(E1*ev[2*p+1], G1*gv[2*p+1]) : fz;
        lacc += w0 + w1;
        wp.hh[p] = pk2(w0, w1);
      }
      uint4* wdst = (uint4*)&wts[r*PITCH + jg];
      wdst[0] = wp.u4[0];
      wdst[1] = wp.u4[1];
    }
    __syncthreads();
    #pragma unroll
    for (int ks=0; ks<4; ++ks){
      int kb = ks*32 + q*8;
      f16x8 a0 = ldb128(&wts[(mt*16+col)*PITCH + kb]);
      f16x8 bv = ldb128(&whs[(nt*16+col)*PITCH + kb]);
      c0 = __builtin_amdgcn_mfma_f32_16x16x32_f16(a0, bv, c0, 0, 0, 0);
    }
  }
  lacc += __shfl_xor(lacc, 1, 64);
  lacc += __shfl_xor(lacc, 2, 64);
  lacc += __shfl_xor(lacc, 4, 64);
  if ((tid & 7) == 0) pl[blk*32 + r] = lacc;
  int dloc = nt*16 + col;
  #pragma unroll
  for (int reg=0; reg<4; ++reg){
    int ir = mt*16 + q*4 + reg;
    pc[(size_t)blk*1024 + ir*32 + dloc] = c0[reg];
  }
}

// ---------------- K4: combine partials + ELU + MLP ----------------------
__global__ void __launch_bounds__(256) classify2(const float* __restrict__ pc,
        const float* __restrict__ pl,
        const float* __restrict__ W1, const float* __restrict__ b1,
        const float* __restrict__ pw, const float* __restrict__ W2, const float* __restrict__ b2,
        float* __restrict__ out){
  __shared__ float efs[4][32];
  int wv = threadIdx.x >> 6;
  int lane = threadIdx.x & 63;
  int row = blockIdx.x*4 + wv;        // 0..B*K1-1
  int b = row >> 8, k = row & 255;
  int kt = k >> 5, r = k & 31;
  int base = (b*8 + kt)*8;
  if (lane < 32){
    float s = 0.f, l = 0.f;
    #pragma unroll
    for (int js=0; js<8; ++js){
      s += pc[(size_t)(base+js)*1024 + r*32 + lane];
      l += pl[(base+js)*32 + r];
    }
    float v = s / l;
    v = v > 0.f ? v : expm1f(v);
    efs[wv][lane] = v;
  }
  __syncthreads();
  const float* ef = efs[wv];
  int c = lane & 31;
  float y = b1[c];
  #pragma unroll 8
  for (int kk=0; kk<32; ++kk) y += ef[kk] * W1[kk*32 + c];
  y = y > 0.f ? y : pw[c]*y;
  float o0 = y * W2[c*2+0];
  float o1 = y * W2[c*2+1];
  #pragma unroll
  for (int o=16;o>0;o>>=1){ o0 += __shfl_xor(o0,o,64); o1 += __shfl_xor(o1,o,64); }
  if (lane==0){ out[row*2+0] = o0 + b2[0]; out[row*2+1] = o1 + b2[1]; }
}

extern "C" void kernel_launch(void* const* d_in, const int* in_sizes, int n_in,
                              void* d_out, int out_size, void* d_ws, size_t ws_size,
                              hipStream_t stream) {
  const float* x    = (const float*)d_in[0];
  const int*   adj  = (const int*)  d_in[1];
  const int*   oh   = (const int*)  d_in[2];
  const float* W    = (const float*)d_in[3];
  const float* a1   = (const float*)d_in[4];
  const float* a2   = (const float*)d_in[5];
  const float* Wo   = (const float*)d_in[6];
  const float* ao1  = (const float*)d_in[7];
  const float* ao2  = (const float*)d_in[8];
  const float* W1   = (const float*)d_in[9];
  const float* b1   = (const float*)d_in[10];
  const float* pw   = (const float*)d_in[11];
  const float* W2   = (const float*)d_in[12];
  const float* b2   = (const float*)d_in[13];
  float* out = (float*)d_out;

  char* base = (char*)d_ws;
  size_t off = 0;
  auto alloc = [&](size_t bytes)->char*{
    char* p = base + off;
    off = (off + bytes + 255) & ~(size_t)255;
    return p;
  };
  unsigned long long* adjbits = (unsigned long long*)alloc((size_t)BB*NN*(NN/64)*8); // 2 MB
  int*   cnt1 = (int*)  alloc((size_t)BB*NN*4);
  _Float16* WhT  = (_Float16*)alloc((size_t)BB*NHEADS*NHID*NN*2);  // 4 MB, [bh][d][i]
  float* ex1  = (float*)alloc((size_t)BB*NHEADS*NN*4);
  float* gx1  = (float*)alloc((size_t)BB*NHEADS*NN*4);
  float* ex2  = (float*)alloc((size_t)BB*NHEADS*NN*4);
  float* gx2  = (float*)alloc((size_t)BB*NHEADS*NN*4);
  float* h1   = (float*)alloc((size_t)BB*NN*(NHEADS*NHID)*4);      // 8 MB
  _Float16* WhT2 = (_Float16*)alloc((size_t)BB*NCLASS*NN*2);       // 512 KB
  float* eo1  = (float*)alloc((size_t)BB*NN*4);
  float* go1  = (float*)alloc((size_t)BB*NN*4);
  float* eo2  = (float*)alloc((size_t)BB*NN*4);
  float* go2  = (float*)alloc((size_t)BB*NN*4);
  float* pc   = (float*)alloc((size_t)256*1024*4);                 // 1 MB partial c
  float* pl   = (float*)alloc((size_t)256*32*4);                   // partial l

  pack_adj<<<BB*NN, 256, 0, stream>>>(adj, adjbits, cnt1);
  wh_proj2<<<BB*NHEADS*(NN/64), 256, 0, stream>>>(x, W, a1, a2, WhT, ex1, gx1, ex2, gx2);
  attn_l1<<<BB*NHEADS*(NN/16), 256, 0, stream>>>(adjbits, WhT, ex1, gx1, ex2, gx2, cnt1, h1);
  out_proj2<<<BB*(NN/64), 256, 0, stream>>>(h1, Wo, ao1, ao2, WhT2, eo1, go1, eo2, go2);
  attn_l2<<<BB*8*8, 256, 0, stream>>>(adjbits, WhT2, eo1, go1, eo2, go2, cnt1, oh, pc, pl);
  classify2<<<(BB*KK1)/4, 256, 0, stream>>>(pc, pl, W1, b1, pw, W2, b2, out);
}